// Round 3
// baseline (468.613 us; speedup 1.0000x reference)
//
#include <hip/hip_runtime.h>

#define N_NODES   50000
#define N_EDGES   800000
#define IN_DIM    100
#define HIDDEN    16
#define N_CLASSES 40
#define BSHIFT    6
#define BNODES    64                                  // nodes per bucket
#define NBUCK     ((N_NODES + BNODES - 1) / BNODES)   // 782
#define NPAD      (NBUCK * BNODES)                    // 50048 (padded h rows)

// ---------------- bucket build ----------------

// deg[b] = number of edges with dst in bucket b. LDS-local hist, one global
// atomic per (block,bucket).
__global__ __launch_bounds__(256) void hist_kernel(const int* __restrict__ dst,
                                                   int* __restrict__ deg) {
    __shared__ int h[NBUCK];
    const int tid = threadIdx.x;
    for (int i = tid; i < NBUCK; i += 256) h[i] = 0;
    __syncthreads();
    for (int e = blockIdx.x * 256 + tid; e < N_EDGES; e += 256 * 256)
        atomicAdd(&h[dst[e] >> BSHIFT], 1);
    __syncthreads();
    for (int i = tid; i < NBUCK; i += 256) {
        const int c = h[i];
        if (c) atomicAdd(&deg[i], c);
    }
}

// Single-block exclusive scan of NBUCK (<=1024) values -> off, cursor.
__global__ __launch_bounds__(256) void scan_kernel(const int* __restrict__ deg,
                                                   int* __restrict__ off,
                                                   int* __restrict__ cursor) {
    __shared__ int lds[256];
    const int t = threadIdx.x;
    int v[4], s = 0;
#pragma unroll
    for (int q = 0; q < 4; ++q) {
        const int i = t * 4 + q;
        v[q] = (i < NBUCK) ? deg[i] : 0;
        s += v[q];
    }
    lds[t] = s;
    __syncthreads();
    int inc = s;
    for (int ofs = 1; ofs < 256; ofs <<= 1) {
        const int y = (t >= ofs) ? lds[t - ofs] : 0;
        __syncthreads();
        inc += y;
        lds[t] = inc;
        __syncthreads();
    }
    int run = inc - s;
#pragma unroll
    for (int q = 0; q < 4; ++q) {
        const int i = t * 4 + q;
        if (i < NBUCK) { off[i] = run; cursor[i] = run; }
        run += v[q];
    }
    if (t == 0) off[NBUCK] = N_EDGES;
}

// Append each edge to its bucket region: record = {src | dst_local<<16, val}.
// Only 782 concurrent write heads -> lines fill while L2-resident.
__global__ __launch_bounds__(256) void scatter_kernel(const int* __restrict__ src,
                                                      const int* __restrict__ dst,
                                                      const float* __restrict__ val,
                                                      int* __restrict__ cursor,
                                                      int2* __restrict__ ebuf) {
    const int e = blockIdx.x * 256 + threadIdx.x;
    const int d = dst[e];
    const int pos = atomicAdd(&cursor[d >> BSHIFT], 1);
    ebuf[pos] = make_int2(src[e] | ((d & (BNODES - 1)) << 16),
                          __float_as_int(val[e]));
}

// ---------------- compute ----------------

// y1 = X @ W1   [N,100] @ [100,16] -> [N,16]; float4 LDS reads both operands.
__global__ __launch_bounds__(256) void gemm_xw1(const float* __restrict__ X,
                                                const float* __restrict__ W,
                                                float* __restrict__ Y) {
    __shared__ __align__(16) float sX[16 * IN_DIM];
    __shared__ __align__(16) float sWt[HIDDEN * IN_DIM];  // W1^T [16][100]
    const int tid  = threadIdx.x;
    const int row0 = blockIdx.x * 16;

    for (int i = tid; i < IN_DIM * HIDDEN; i += 256) {
        const int k = i >> 4, j = i & 15;
        sWt[j * IN_DIM + k] = W[i];
    }
    const float* xbase = X + (size_t)row0 * IN_DIM;
    for (int i = tid; i < 16 * IN_DIM; i += 256) sX[i] = xbase[i];
    __syncthreads();

    const int r = tid >> 4, j = tid & 15;
    const float4* ax = (const float4*)&sX[r * IN_DIM];
    const float4* bw = (const float4*)&sWt[j * IN_DIM];
    float acc = 0.f;
#pragma unroll
    for (int q = 0; q < IN_DIM / 4; ++q) {
        const float4 a = ax[q];
        const float4 b = bw[q];
        acc = fmaf(a.x, b.x, acc);
        acc = fmaf(a.y, b.y, acc);
        acc = fmaf(a.z, b.z, acc);
        acc = fmaf(a.w, b.w, acc);
    }
    Y[(size_t)(row0 + r) * HIDDEN + j] = acc;
}

// One block per bucket. Accumulate the 64x16 z-tile in LDS via ds_add_f32.
// FINAL=false: write relu(z) to outp (padded [NPAD,16]).
// FINAL=true : epilogue out[n] = log_softmax(z[n] @ W2), written directly.
template <bool FINAL>
__global__ __launch_bounds__(512) void spmm_bucket(const int* __restrict__ off,
                                                   const int2* __restrict__ ebuf,
                                                   const float* __restrict__ X,
                                                   const float* __restrict__ W2,
                                                   float* __restrict__ outp) {
    __shared__ float tile[BNODES * HIDDEN];          // 4 KB
    __shared__ float sW2[HIDDEN * N_CLASSES];        // 2.5 KB
    const int tid = threadIdx.x;
    const int b = blockIdx.x;

    for (int i = tid; i < BNODES * HIDDEN; i += 512) tile[i] = 0.f;
    if (FINAL)
        for (int i = tid; i < HIDDEN * N_CLASSES; i += 512) sW2[i] = W2[i];
    __syncthreads();

    const int g = tid >> 4, j = tid & 15;            // 32 groups of 16 lanes
    const int e1 = off[b + 1];
    for (int i = off[b] + g; i < e1; i += 32) {
        const int2 e = ebuf[i];                      // broadcast within group
        const float x = X[(size_t)(e.x & 0xFFFF) * HIDDEN + j];
        unsafeAtomicAdd(&tile[((e.x >> 16) & (BNODES - 1)) * HIDDEN + j],
                        __int_as_float(e.y) * x);
    }
    __syncthreads();

    if (!FINAL) {
        if (tid < 256) {
            float4 t = ((const float4*)tile)[tid];
            t.x = fmaxf(t.x, 0.f); t.y = fmaxf(t.y, 0.f);
            t.z = fmaxf(t.z, 0.f); t.w = fmaxf(t.w, 0.f);
            ((float4*)outp)[(size_t)b * 256 + tid] = t;   // padded, no guard
        }
    } else {
        const int nl = tid >> 3;                     // local node, 8 lanes each
        const int n  = b * BNODES + nl;
        const int c0 = (tid & 7) * 5;                // 5 classes per lane
        float z[HIDDEN];
        const float4* zp = (const float4*)&tile[nl * HIDDEN];
#pragma unroll
        for (int q = 0; q < 4; ++q) {
            const float4 t = zp[q];
            z[q * 4 + 0] = t.x; z[q * 4 + 1] = t.y;
            z[q * 4 + 2] = t.z; z[q * 4 + 3] = t.w;
        }
        float o[5];
#pragma unroll
        for (int c = 0; c < 5; ++c) {
            float acc = 0.f;
#pragma unroll
            for (int k = 0; k < HIDDEN; ++k)
                acc = fmaf(z[k], sW2[k * N_CLASSES + c0 + c], acc);
            o[c] = acc;
        }
        float m = -INFINITY;
#pragma unroll
        for (int c = 0; c < 5; ++c) m = fmaxf(m, o[c]);
        m = fmaxf(m, __shfl_xor(m, 1));
        m = fmaxf(m, __shfl_xor(m, 2));
        m = fmaxf(m, __shfl_xor(m, 4));
        float s = 0.f;
#pragma unroll
        for (int c = 0; c < 5; ++c) s += __expf(o[c] - m);
        s += __shfl_xor(s, 1);
        s += __shfl_xor(s, 2);
        s += __shfl_xor(s, 4);
        const float lse = m + __logf(s);
        if (n < N_NODES) {
            float* op = outp + (size_t)n * N_CLASSES + c0;
#pragma unroll
            for (int c = 0; c < 5; ++c) op[c] = o[c] - lse;
        }
    }
}

extern "C" void kernel_launch(void* const* d_in, const int* in_sizes, int n_in,
                              void* d_out, int out_size, void* d_ws, size_t ws_size,
                              hipStream_t stream) {
    const float* features = (const float*)d_in[0];  // [50000,100]
    const int*   edge_src = (const int*)d_in[1];    // [800000]
    const int*   edge_dst = (const int*)d_in[2];    // [800000]
    const float* edge_val = (const float*)d_in[3];  // [800000]
    const float* W1       = (const float*)d_in[4];  // [100,16]
    const float* W2       = (const float*)d_in[5];  // [16,40]
    float*       out      = (float*)d_out;          // [50000,40]

    char* ws = (char*)d_ws;
    int2*  ebuf   = (int2*)ws;   ws += (size_t)N_EDGES * sizeof(int2);       // 6.4 MB
    float* y1     = (float*)ws;  ws += (size_t)N_NODES * HIDDEN * sizeof(float);
    float* h      = (float*)ws;  ws += (size_t)NPAD * HIDDEN * sizeof(float);
    int*   deg    = (int*)ws;    ws += (NBUCK + 1) * sizeof(int);
    int*   off    = (int*)ws;    ws += (NBUCK + 1) * sizeof(int);
    int*   cursor = (int*)ws;    ws += (NBUCK + 1) * sizeof(int);

    // bucket build (amortized over both SpMMs)
    hipMemsetAsync(deg, 0, NBUCK * sizeof(int), stream);
    hist_kernel<<<256, 256, 0, stream>>>(edge_dst, deg);
    scan_kernel<<<1, 256, 0, stream>>>(deg, off, cursor);
    scatter_kernel<<<N_EDGES / 256, 256, 0, stream>>>(edge_src, edge_dst, edge_val,
                                                      cursor, ebuf);

    // y1 = X @ W1
    gemm_xw1<<<N_NODES / 16, 256, 0, stream>>>(features, W1, y1);

    // h = relu(A @ y1)
    spmm_bucket<false><<<NBUCK, 512, 0, stream>>>(off, ebuf, y1, W2, h);
    // out = log_softmax((A @ h) @ W2)
    spmm_bucket<true><<<NBUCK, 512, 0, stream>>>(off, ebuf, h, W2, out);
}

// Round 4
// 310.222 us; speedup vs baseline: 1.5106x; 1.5106x over previous
//
#include <hip/hip_runtime.h>

#define N_NODES   50000
#define N_EDGES   800000
#define IN_DIM    100
#define HIDDEN    16
#define N_CLASSES 40
#define BSHIFT    6
#define BNODES    64                                  // nodes per bucket
#define NBUCK     ((N_NODES + BNODES - 1) / BNODES)   // 782
#define NPAD      (NBUCK * BNODES)                    // 50048 (padded h rows)
#define NPB       128                                 // partition blocks
#define EPB       (N_EDGES / NPB)                     // 6250 edges per block

// ---------------- deterministic bucket partition ----------------

// Per-block LDS histogram of its 6250-edge chunk; write bucket-major
// histG[bucket][block] (no global atomics).
__global__ __launch_bounds__(256) void hist_kernel(const int* __restrict__ dst,
                                                   int* __restrict__ histG) {
    __shared__ int h[NBUCK];
    const int tid = threadIdx.x;
    for (int i = tid; i < NBUCK; i += 256) h[i] = 0;
    __syncthreads();
    const int base = blockIdx.x * EPB;
    for (int i = tid; i < EPB; i += 256)
        atomicAdd(&h[dst[base + i] >> BSHIFT], 1);
    __syncthreads();
    for (int i = tid; i < NBUCK; i += 256)
        histG[i * NPB + blockIdx.x] = h[i];
}

// One block: bucket totals (sum of 128 per-block counts) + exclusive scan
// over 782 buckets -> off[].
__global__ __launch_bounds__(256) void scan_kernel(const int* __restrict__ histG,
                                                   int* __restrict__ off) {
    __shared__ int lds[256];
    const int t = threadIdx.x;
    int v[4], s = 0;
#pragma unroll
    for (int q = 0; q < 4; ++q) {
        const int bu = t * 4 + q;
        int sum = 0;
        if (bu < NBUCK) {
            const int4* p = (const int4*)(histG + bu * NPB);
            for (int j = 0; j < NPB / 4; ++j) {
                const int4 x = p[j];
                sum += x.x + x.y + x.z + x.w;
            }
        }
        v[q] = sum;
        s += sum;
    }
    lds[t] = s;
    __syncthreads();
    int inc = s;
    for (int ofs = 1; ofs < 256; ofs <<= 1) {
        const int y = (t >= ofs) ? lds[t - ofs] : 0;
        __syncthreads();
        inc += y;
        lds[t] = inc;
        __syncthreads();
    }
    int run = inc - s;
#pragma unroll
    for (int q = 0; q < 4; ++q) {
        const int bu = t * 4 + q;
        if (bu < NBUCK) off[bu] = run;
        run += v[q];
    }
    if (t == 0) off[NBUCK] = N_EDGES;
}

// One block per bucket: exclusive scan of the 128 per-block counts + bucket
// base -> exact start position per (bucket, block). In place.
__global__ __launch_bounds__(128) void colscan_kernel(int* __restrict__ histG,
                                                      const int* __restrict__ off) {
    __shared__ int lds[128];
    const int t = threadIdx.x, bu = blockIdx.x;
    const int v = histG[bu * NPB + t];
    lds[t] = v;
    __syncthreads();
    int inc = v;
    for (int ofs = 1; ofs < 128; ofs <<= 1) {
        const int y = (t >= ofs) ? lds[t - ofs] : 0;
        __syncthreads();
        inc += y;
        lds[t] = inc;
        __syncthreads();
    }
    histG[bu * NPB + t] = off[bu] + inc - v;
}

// Each block re-reads its chunk; positions come from LDS cursors seeded with
// the deterministic starts. Zero global atomics; ~8 records per
// (block,bucket) run -> full-line writes.
__global__ __launch_bounds__(256) void scatter_kernel(const int* __restrict__ src,
                                                      const int* __restrict__ dst,
                                                      const float* __restrict__ val,
                                                      const int* __restrict__ start,
                                                      int2* __restrict__ ebuf) {
    __shared__ int cur[NBUCK];
    const int t = threadIdx.x, b = blockIdx.x;
    for (int i = t; i < NBUCK; i += 256) cur[i] = start[i * NPB + b];
    __syncthreads();
    const int base = b * EPB;
    for (int i = t; i < EPB; i += 256) {
        const int d = dst[base + i];
        const int pos = atomicAdd(&cur[d >> BSHIFT], 1);
        ebuf[pos] = make_int2(src[base + i] | ((d & (BNODES - 1)) << 16),
                              __float_as_int(val[base + i]));
    }
}

// ---------------- compute ----------------

// y1 = X @ W1   [N,100] @ [100,16] -> [N,16]; float4 LDS reads both operands.
__global__ __launch_bounds__(256) void gemm_xw1(const float* __restrict__ X,
                                                const float* __restrict__ W,
                                                float* __restrict__ Y) {
    __shared__ __align__(16) float sX[16 * IN_DIM];
    __shared__ __align__(16) float sWt[HIDDEN * IN_DIM];  // W1^T [16][100]
    const int tid  = threadIdx.x;
    const int row0 = blockIdx.x * 16;

    for (int i = tid; i < IN_DIM * HIDDEN; i += 256) {
        const int k = i >> 4, j = i & 15;
        sWt[j * IN_DIM + k] = W[i];
    }
    const float* xbase = X + (size_t)row0 * IN_DIM;
    for (int i = tid; i < 16 * IN_DIM; i += 256) sX[i] = xbase[i];
    __syncthreads();

    const int r = tid >> 4, j = tid & 15;
    const float4* ax = (const float4*)&sX[r * IN_DIM];
    const float4* bw = (const float4*)&sWt[j * IN_DIM];
    float acc = 0.f;
#pragma unroll
    for (int q = 0; q < IN_DIM / 4; ++q) {
        const float4 a = ax[q];
        const float4 b = bw[q];
        acc = fmaf(a.x, b.x, acc);
        acc = fmaf(a.y, b.y, acc);
        acc = fmaf(a.z, b.z, acc);
        acc = fmaf(a.w, b.w, acc);
    }
    Y[(size_t)(row0 + r) * HIDDEN + j] = acc;
}

// One block per bucket. Accumulate the 64x16 z-tile in LDS atomics.
// FINAL=false: write relu(z) to outp (padded [NPAD,16]).
// FINAL=true : out[n] = log_softmax(z[n] @ W2), written directly.
template <bool FINAL>
__global__ __launch_bounds__(512) void spmm_bucket(const int* __restrict__ off,
                                                   const int2* __restrict__ ebuf,
                                                   const float* __restrict__ X,
                                                   const float* __restrict__ W2,
                                                   float* __restrict__ outp) {
    __shared__ float tile[BNODES * HIDDEN];          // 4 KB
    __shared__ float sW2[HIDDEN * N_CLASSES];        // 2.5 KB
    const int tid = threadIdx.x;
    const int b = blockIdx.x;

    for (int i = tid; i < BNODES * HIDDEN; i += 512) tile[i] = 0.f;
    if (FINAL)
        for (int i = tid; i < HIDDEN * N_CLASSES; i += 512) sW2[i] = W2[i];
    __syncthreads();

    const int g = tid >> 4, j = tid & 15;            // 32 groups of 16 lanes
    const int e1 = off[b + 1];
    for (int i = off[b] + g; i < e1; i += 32) {
        const int2 e = ebuf[i];                      // broadcast within group
        const float x = X[(size_t)(e.x & 0xFFFF) * HIDDEN + j];
        atomicAdd(&tile[((e.x >> 16) & (BNODES - 1)) * HIDDEN + j],
                  __int_as_float(e.y) * x);
    }
    __syncthreads();

    if (!FINAL) {
        if (tid < 256) {
            float4 t = ((const float4*)tile)[tid];
            t.x = fmaxf(t.x, 0.f); t.y = fmaxf(t.y, 0.f);
            t.z = fmaxf(t.z, 0.f); t.w = fmaxf(t.w, 0.f);
            ((float4*)outp)[(size_t)b * 256 + tid] = t;   // padded, no guard
        }
    } else {
        const int nl = tid >> 3;                     // local node, 8 lanes each
        const int n  = b * BNODES + nl;
        const int c0 = (tid & 7) * 5;                // 5 classes per lane
        float z[HIDDEN];
        const float4* zp = (const float4*)&tile[nl * HIDDEN];
#pragma unroll
        for (int q = 0; q < 4; ++q) {
            const float4 t = zp[q];
            z[q * 4 + 0] = t.x; z[q * 4 + 1] = t.y;
            z[q * 4 + 2] = t.z; z[q * 4 + 3] = t.w;
        }
        float o[5];
#pragma unroll
        for (int c = 0; c < 5; ++c) {
            float acc = 0.f;
#pragma unroll
            for (int k = 0; k < HIDDEN; ++k)
                acc = fmaf(z[k], sW2[k * N_CLASSES + c0 + c], acc);
            o[c] = acc;
        }
        float m = -INFINITY;
#pragma unroll
        for (int c = 0; c < 5; ++c) m = fmaxf(m, o[c]);
        m = fmaxf(m, __shfl_xor(m, 1));
        m = fmaxf(m, __shfl_xor(m, 2));
        m = fmaxf(m, __shfl_xor(m, 4));
        float s = 0.f;
#pragma unroll
        for (int c = 0; c < 5; ++c) s += __expf(o[c] - m);
        s += __shfl_xor(s, 1);
        s += __shfl_xor(s, 2);
        s += __shfl_xor(s, 4);
        const float lse = m + __logf(s);
        if (n < N_NODES) {
            float* op = outp + (size_t)n * N_CLASSES + c0;
#pragma unroll
            for (int c = 0; c < 5; ++c) op[c] = o[c] - lse;
        }
    }
}

extern "C" void kernel_launch(void* const* d_in, const int* in_sizes, int n_in,
                              void* d_out, int out_size, void* d_ws, size_t ws_size,
                              hipStream_t stream) {
    const float* features = (const float*)d_in[0];  // [50000,100]
    const int*   edge_src = (const int*)d_in[1];    // [800000]
    const int*   edge_dst = (const int*)d_in[2];    // [800000]
    const float* edge_val = (const float*)d_in[3];  // [800000]
    const float* W1       = (const float*)d_in[4];  // [100,16]
    const float* W2       = (const float*)d_in[5];  // [16,40]
    float*       out      = (float*)d_out;          // [50000,40]

    char* ws = (char*)d_ws;
    int2*  ebuf  = (int2*)ws;   ws += (size_t)N_EDGES * sizeof(int2);        // 6.4 MB
    float* y1    = (float*)ws;  ws += (size_t)N_NODES * HIDDEN * sizeof(float);
    float* h     = (float*)ws;  ws += (size_t)NPAD * HIDDEN * sizeof(float);
    int*   histG = (int*)ws;    ws += (size_t)NBUCK * NPB * sizeof(int);     // 400 KB
    int*   off   = (int*)ws;    ws += (NBUCK + 1) * sizeof(int);

    // deterministic bucket partition (amortized over both SpMMs)
    hist_kernel<<<NPB, 256, 0, stream>>>(edge_dst, histG);
    scan_kernel<<<1, 256, 0, stream>>>(histG, off);
    colscan_kernel<<<NBUCK, 128, 0, stream>>>(histG, off);
    scatter_kernel<<<NPB, 256, 0, stream>>>(edge_src, edge_dst, edge_val,
                                            histG, ebuf);

    // y1 = X @ W1
    gemm_xw1<<<N_NODES / 16, 256, 0, stream>>>(features, W1, y1);

    // h = relu(A @ y1)
    spmm_bucket<false><<<NBUCK, 512, 0, stream>>>(off, ebuf, y1, W2, h);
    // out = log_softmax((A @ h) @ W2)
    spmm_bucket<true><<<NBUCK, 512, 0, stream>>>(off, ebuf, h, W2, out);
}